// Round 20
// baseline (285.738 us; speedup 1.0000x reference)
//
#include <hip/hip_runtime.h>
#include <math.h>

#define HCDIM 256   // H*C
#define HEADS 8
#define CH 32
#define NEG 0.2f
#define LOG2E 1.4426950408889634f

typedef __attribute__((ext_vector_type(8))) short bf16x8;
typedef __attribute__((ext_vector_type(4))) float f32x4;

__device__ __forceinline__ float4 ld4(const float* p){ return *reinterpret_cast<const float4*>(p); }
__device__ __forceinline__ void st4(float* p, float a, float b, float c, float d){
    float4 v; v.x=a; v.y=b; v.z=c; v.w=d; *reinterpret_cast<float4*>(p)=v;
}
__device__ __forceinline__ unsigned short f2bf(float f){
    union { float f; unsigned u; } x; x.f = f;
    unsigned r = x.u + 0x7fff + ((x.u >> 16) & 1);   // RNE
    return (unsigned short)(r >> 16);
}
__device__ __forceinline__ float bf2f(unsigned short u){
    union { unsigned u; float f; } x; x.u = (unsigned)u << 16; return x.f;
}
// unpack 8 bf16 (uint4) -> 8 f32
__device__ __forceinline__ void unpk8(uint4 u, float* x){
    x[0] = __uint_as_float(u.x << 16); x[1] = __uint_as_float(u.x & 0xffff0000u);
    x[2] = __uint_as_float(u.y << 16); x[3] = __uint_as_float(u.y & 0xffff0000u);
    x[4] = __uint_as_float(u.z << 16); x[5] = __uint_as_float(u.z & 0xffff0000u);
    x[6] = __uint_as_float(u.w << 16); x[7] = __uint_as_float(u.w & 0xffff0000u);
}
// exact 4-lane (quad) sum via DPP
__device__ __forceinline__ float dpp_sum4(float p){
    p += __int_as_float(__builtin_amdgcn_mov_dpp(__float_as_int(p), 0xB1, 0xf, 0xf, true));
    p += __int_as_float(__builtin_amdgcn_mov_dpp(__float_as_int(p), 0x4E, 0xf, 0xf, true));
    return p;
}

// ---------- zero degsum ----------
__global__ void k_zero(unsigned long long* __restrict__ p, int n){
    int i = blockIdx.x*blockDim.x + threadIdx.x;
    if (i < n) p[i] = 0ULL;
}

// ---------- FUSED preprocessing launch: count | layer-0 dual GEMM (din=3) | cvtw2 ----------
__global__ __launch_bounds__(256) void k_fused_pre(
        const int* __restrict__ dst, const float* __restrict__ eattr,
        unsigned long long* __restrict__ degsum, int* __restrict__ rank, int E,
        const float* __restrict__ x,
        const float* __restrict__ Wl0, const float* __restrict__ bl0,
        const float* __restrict__ Wr0, const float* __restrict__ br0,
        unsigned short* __restrict__ XL, unsigned short* __restrict__ XR, int N,
        const float* __restrict__ Wl1, const float* __restrict__ Wr1,
        const float* __restrict__ Wl2, const float* __restrict__ Wr2,
        unsigned short* __restrict__ Wt1, unsigned short* __restrict__ Wt2,
        int nbCount, int nbGemm)
{
    __shared__ float hs[48];
    int b = blockIdx.x;
    int tid = threadIdx.x;
    if (b < nbCount){
        // ONE packed 64-bit atomic per edge: hi bits deg, low 40 = lsum (2^-20 fp).
        int e = b*256 + tid;
        if (e < E){
            int d = dst[e];
            unsigned long long pk = (1ULL << 40) |
                (unsigned long long)__float2uint_rn(eattr[e] * 1048576.0f);
            unsigned long long old = atomicAdd(&degsum[d], pk);
            rank[e] = (int)(old >> 40);
        }
    } else if (b < nbCount + nbGemm){
        int gb = b - nbCount;
        int row0 = gb * 16;
        if (tid < 48){
            int r = tid / 3, c = tid - r*3;
            int row = row0 + r;
            hs[tid] = (row < N) ? x[(size_t)row*3 + c] : 0.f;
        }
        __syncthreads();
        int j = tid;
        float wl0 = Wl0[j], wl1 = Wl0[256 + j], wl2 = Wl0[512 + j];
        float wr0 = Wr0[j], wr1 = Wr0[256 + j], wr2 = Wr0[512 + j];
        float blj = bl0[j], brj = br0[j];
        #pragma unroll
        for (int r = 0; r < 16; r++){
            int row = row0 + r;
            if (row < N){
                float h0 = hs[r*3], h1 = hs[r*3+1], h2 = hs[r*3+2];
                float al = blj + h0*wl0 + h1*wl1 + h2*wl2;
                float ar = brj + h0*wr0 + h1*wr1 + h2*wr2;
                XL[(size_t)row*HCDIM + j] = f2bf(al);
                XR[(size_t)row*HCDIM + j] = f2bf(ar);
            }
        }
    } else {
        int idx = (b - nbCount - nbGemm)*256 + tid;   // [0, 2*512*256)
        int half = idx >> 17;
        int j = idx & 131071;
        int nout = j >> 8, k = j & 255;
        const float* Wl = half ? Wl2 : Wl1;
        const float* Wr = half ? Wr2 : Wr1;
        float v = (nout < 256) ? Wl[k*HCDIM + nout] : Wr[k*HCDIM + (nout - 256)];
        (half ? Wt2 : Wt1)[j] = f2bf(v);
    }
}

// ---- scan pass 1: per-block inclusive scan + block totals + lattr ----
__global__ __launch_bounds__(1024) void k_scan1(
        const unsigned long long* __restrict__ degsum,
        int* __restrict__ offs, float* __restrict__ lattr,
        int* __restrict__ partials, int n){
    __shared__ int wsum[16];
    int tid = threadIdx.x;
    int i = blockIdx.x*1024 + tid;
    int lane = tid & 63, wid = tid >> 6;
    int x = 0;
    if (i < n){
        unsigned long long ds = degsum[i];
        x = (int)(ds >> 40);
        float ls = (float)(ds & ((1ULL << 40) - 1)) * (1.0f/1048576.0f);
        lattr[i] = ls / fmaxf((float)x, 1.0f);
    }
    int v = x;
    #pragma unroll
    for (int o = 1; o < 64; o <<= 1){
        int y = __shfl_up(v, o);
        if (lane >= o) v += y;
    }
    if (lane == 63) wsum[wid] = v;
    __syncthreads();
    if (wid == 0 && lane < 16){
        int w = wsum[lane];
        #pragma unroll
        for (int o = 1; o < 16; o <<= 1){
            int y = __shfl_up(w, o);
            if (lane >= o) w += y;
        }
        wsum[lane] = w;
    }
    __syncthreads();
    int incl = v + (wid > 0 ? wsum[wid-1] : 0);
    if (i < n) offs[i+1] = incl;
    if (tid == 1023) partials[blockIdx.x] = incl;
}

// ---- scan pass 2: add block base (computed in-kernel; nb <= 64) ----
__global__ __launch_bounds__(1024) void k_scan3(int* __restrict__ offs,
                                                const int* __restrict__ partials, int n){
    __shared__ int sbase;
    if (threadIdx.x < 64){
        int lane = threadIdx.x;
        int vv = (lane < (int)blockIdx.x) ? partials[lane] : 0;
        #pragma unroll
        for (int o = 1; o < 64; o <<= 1) vv += __shfl_xor(vv, o);
        if (lane == 0) sbase = vv;
    }
    __syncthreads();
    int i = blockIdx.x*1024 + threadIdx.x;
    if (i < n) offs[i+1] += sbase;
    if (i == 0) offs[0] = 0;
}

// csr.x holds PRE-SHIFTED byte offset (src * HCDIM * 2); NO atomics.
__global__ void k_scatter(const int* __restrict__ src, const int* __restrict__ dst,
                          const float* __restrict__ eattr, const int* __restrict__ offs,
                          const int* __restrict__ rank, int2* csr, int E){
    int e = blockIdx.x*blockDim.x + threadIdx.x;
    if (e < E){
        int d = dst[e];
        int pos = offs[d] + rank[e];
        int2 pk; pk.x = src[e] << 9; pk.y = __float_as_int(eattr[e]);
        csr[pos] = pk;
    }
}

// ---------- bf16 MFMA GEMM: [xl | xr] = h @ [Wl | Wr] + [bl | br] ----------
// 1D grid with XCD-aware bijective swizzle: the 4 col-chunks sharing the same
// A-rows land on the SAME XCD -> A fetched once per XCD L2, not 4x.
#define BM 128
#define BN 128
#define BK 32
#define LDK 40   // padded LDS stride (bf16 elems)

__global__ __launch_bounds__(256) void k_mfma_gemm(
        const unsigned short* __restrict__ h,
        const unsigned short* __restrict__ Wt,
        const float* __restrict__ bl, const float* __restrict__ br,
        unsigned short* __restrict__ xl, unsigned short* __restrict__ xr, int n)
{
    __shared__ unsigned short As[BM*LDK];
    __shared__ unsigned short Bs[BN*LDK];
    int tid = threadIdx.x;
    int total = gridDim.x;
    int q = total >> 3, rr = total & 7;
    int xcd = blockIdx.x & 7, slot = blockIdx.x >> 3;
    int logical = (xcd < rr ? xcd*(q+1) : rr*(q+1) + (xcd-rr)*q) + slot;
    int row0 = (logical >> 2) * BM;
    int col0 = (logical & 3) * BN;      // 0,128,256,384 over [Wl|Wr]

    int l = tid & 63, w = tid >> 6;
    int wm = (w >> 1) * 64, wn = (w & 1) * 64;

    f32x4 acc[4][4] = {};

    int srow = tid >> 1;
    int skoff = (tid & 1) * 16;

    for (int kt = 0; kt < 8; ++kt){
        int kb = kt * BK;
        uint4 av0, av1;
        int grow = row0 + srow;
        if (grow < n){
            const uint4* ap = reinterpret_cast<const uint4*>(h + (size_t)grow*HCDIM + kb + skoff);
            av0 = ap[0]; av1 = ap[1];
        } else {
            av0.x=av0.y=av0.z=av0.w=0u; av1 = av0;
        }
        const uint4* bp = reinterpret_cast<const uint4*>(Wt + (size_t)(col0+srow)*HCDIM + kb + skoff);
        uint4 bv0 = bp[0], bv1 = bp[1];

        __syncthreads();   // previous iteration's LDS reads complete

        *reinterpret_cast<uint4*>(&As[srow*LDK + skoff])     = av0;
        *reinterpret_cast<uint4*>(&As[srow*LDK + skoff + 8]) = av1;
        *reinterpret_cast<uint4*>(&Bs[srow*LDK + skoff])     = bv0;
        *reinterpret_cast<uint4*>(&Bs[srow*LDK + skoff + 8]) = bv1;

        __syncthreads();

        bf16x8 af[4], bfr[4];
        #pragma unroll
        for (int m = 0; m < 4; m++)
            af[m] = *reinterpret_cast<const bf16x8*>(&As[(wm + m*16 + (l & 15))*LDK + ((l >> 4)*8)]);
        #pragma unroll
        for (int nn = 0; nn < 4; nn++)
            bfr[nn] = *reinterpret_cast<const bf16x8*>(&Bs[(wn + nn*16 + (l & 15))*LDK + ((l >> 4)*8)]);
        #pragma unroll
        for (int m = 0; m < 4; m++)
            #pragma unroll
            for (int nn = 0; nn < 4; nn++)
                acc[m][nn] = __builtin_amdgcn_mfma_f32_16x16x32_bf16(af[m], bfr[nn], acc[m][nn], 0, 0, 0);
    }

    unsigned short* dstp; const float* biasp; int cbase;
    if (col0 < 256){ dstp = xl; biasp = bl; cbase = col0; }
    else           { dstp = xr; biasp = br; cbase = col0 - 256; }

    #pragma unroll
    for (int nn = 0; nn < 4; nn++){
        int gc = cbase + wn + nn*16 + (l & 15);
        float bb = biasp[gc];
        #pragma unroll
        for (int m = 0; m < 4; m++){
            int r0 = row0 + wm + m*16 + ((l >> 4) * 4);
            #pragma unroll
            for (int v = 0; v < 4; v++){
                int rr2 = r0 + v;
                if (rr2 < n) dstp[(size_t)rr2*HCDIM + gc] = f2bf(acc[m][nn][v] + bb);
            }
        }
    }
}

// ---------- fused GATv2 edge kernel ----------
// PERSISTENT one-wave blocks: grid-strided over nodes so We/att register state
// is loaded once per wave (not per node) and launch/retire amortizes ~6x.
// TWO edges per wave-step (lanes 0-31 / 32-63), each lane owns 8 channels.
// 2-deep software pipeline; quad-DPP logit reduce; no-max softmax.
__global__ __launch_bounds__(64) void k_gat(
        const unsigned short* __restrict__ xl, const unsigned short* __restrict__ xr,
        const int2* __restrict__ csr,
        const int* __restrict__ offs, const float* __restrict__ lattr,
        const float* __restrict__ We, const float* __restrict__ att,
        const float* __restrict__ bias,
        unsigned short* __restrict__ hout_bf, float* __restrict__ hout_f,
        int n, int concat)
{
    int lane = threadIdx.x;
    int sub = lane >> 5;             // edge slot (0/1)
    int l5  = lane & 31;             // channel group: ch [l5*8, l5*8+8)
    const char* xlb = reinterpret_cast<const char*>(xl);
    const size_t cbb = (size_t)l5 * 16;   // byte offset within 512B row

    // wave-lifetime state (hoisted out of the node loop)
    float We8[8], at8[8];
    {
        const float* wp = We + l5*8;
        const float* ap = att + l5*8;
        #pragma unroll
        for (int c = 0; c < 8; c++){ We8[c] = wp[c]; at8[c] = ap[c]*LOG2E; }
    }
    float b8[8];
    if (concat){
        const float* bp = bias + l5*8;
        #pragma unroll
        for (int c = 0; c < 8; c++) b8[c] = bp[c];
    } else if (lane < 4){
        const float* bp = bias + lane*8;
        #pragma unroll
        for (int c = 0; c < 8; c++) b8[c] = bp[c];
    }

    for (int v = blockIdx.x; v < n; v += gridDim.x){
        float xr8[8];
        {
            uint4 u = *reinterpret_cast<const uint4*>(xr + (size_t)v*HCDIM + l5*8);
            unpk8(u, xr8);
        }
        int pbeg = offs[v], pend = offs[v+1];
        float la = lattr[v];

        float s = 0.f;
        float acc[8] = {0.f,0.f,0.f,0.f,0.f,0.f,0.f,0.f};

        auto estep = [&](uint4 xu, float ea){
            float x8[8];
            unpk8(xu, x8);
            float part = 0.f;
            #pragma unroll
            for (int c = 0; c < 8; c++){
                float t = x8[c] + fmaf(ea, We8[c], xr8[c]);
                t = fmaxf(t, NEG*t);              // leaky relu, slope<1
                part = fmaf(t, at8[c], part);
            }
            part = dpp_sum4(part);               // head logit (log2 units)
            float w = __builtin_amdgcn_exp2f(part);
            s += w;
            #pragma unroll
            for (int c = 0; c < 8; c++) acc[c] = fmaf(w, x8[c], acc[c]);
        };

        // prologue: slot A = self-loop, slot B = first real edge
        {
            uint4 xu; float ea; bool act;
            if (sub == 0){
                xu = *reinterpret_cast<const uint4*>(xlb + ((size_t)v << 9) + cbb);
                ea = la; act = true;
            } else {
                act = (pbeg < pend);
                if (act){
                    int2 e = csr[pbeg];
                    xu = *reinterpret_cast<const uint4*>(xlb + (size_t)(unsigned)e.x + cbb);
                    ea = __int_as_float(e.y);
                }
            }
            if (act) estep(xu, ea);
        }

        // main loop: 2 edges per step, 2-deep software pipeline
        int p = pbeg + 1;                 // uniform across wave
        int2 e0, e1; uint4 x0, x1; bool a0 = false, a1 = false;
        {
            int i0 = p + sub;
            a0 = (i0 < pend);
            if (a0){
                e0 = csr[i0];
                x0 = *reinterpret_cast<const uint4*>(xlb + (size_t)(unsigned)e0.x + cbb);
            }
            int i1 = p + 2 + sub;
            a1 = (i1 < pend);
            if (a1){
                e1 = csr[i1];
                x1 = *reinterpret_cast<const uint4*>(xlb + (size_t)(unsigned)e1.x + cbb);
            }
        }
        for (; p < pend; p += 2){
            uint4 cx = x0; float cea = __int_as_float(e0.y); bool ca = a0;
            x0 = x1; e0 = e1; a0 = a1;
            int nx = p + 4 + sub;
            a1 = (nx < pend);
            if (a1){
                e1 = csr[nx];
                x1 = *reinterpret_cast<const uint4*>(xlb + (size_t)(unsigned)e1.x + cbb);
            }
            if (ca) estep(cx, cea);
        }

        // merge the two edge-slot halves (lane l <-> lane l^32)
        s += __shfl_xor(s, 32);
        #pragma unroll
        for (int c = 0; c < 8; c++) acc[c] += __shfl_xor(acc[c], 32);

        float inv = 1.f / s;
        if (concat){
            if (sub == 0){
                float r[8];
                #pragma unroll
                for (int c = 0; c < 8; c++) r[c] = fmaxf(fmaf(acc[c], inv, b8[c]), 0.f);
                uint4 o;
                o.x = (unsigned)f2bf(r[0]) | ((unsigned)f2bf(r[1]) << 16);
                o.y = (unsigned)f2bf(r[2]) | ((unsigned)f2bf(r[3]) << 16);
                o.z = (unsigned)f2bf(r[4]) | ((unsigned)f2bf(r[5]) << 16);
                o.w = (unsigned)f2bf(r[6]) | ((unsigned)f2bf(r[7]) << 16);
                *reinterpret_cast<uint4*>(hout_bf + (size_t)v*HCDIM + l5*8) = o;
            }
        } else {
            float o8[8];
            #pragma unroll
            for (int c = 0; c < 8; c++) o8[c] = acc[c]*inv;   // normalize per head first
            #pragma unroll
            for (int m = 4; m <= 16; m <<= 1)
                #pragma unroll
                for (int c = 0; c < 8; c++) o8[c] += __shfl_xor(o8[c], m);  // sum heads
            if (lane < 4){
                float* op = hout_f + (size_t)v*CH + lane*8;
                st4(op,   fmaxf(fmaf(o8[0], 0.125f, b8[0]), 0.f),
                          fmaxf(fmaf(o8[1], 0.125f, b8[1]), 0.f),
                          fmaxf(fmaf(o8[2], 0.125f, b8[2]), 0.f),
                          fmaxf(fmaf(o8[3], 0.125f, b8[3]), 0.f));
                st4(op+4, fmaxf(fmaf(o8[4], 0.125f, b8[4]), 0.f),
                          fmaxf(fmaf(o8[5], 0.125f, b8[5]), 0.f),
                          fmaxf(fmaf(o8[6], 0.125f, b8[6]), 0.f),
                          fmaxf(fmaf(o8[7], 0.125f, b8[7]), 0.f));
            }
        }
    }
}

// ---------- fused heads stage 1: node log-softmax out + Pe = h @ ehW1 (bf16) ----------
__global__ __launch_bounds__(256) void k_heads(
        const float* __restrict__ hf,
        const float* __restrict__ nW1, const float* __restrict__ nb1,
        const float* __restrict__ nW2, const float* __restrict__ nb2,
        const float* __restrict__ eW1,
        float* __restrict__ out, unsigned short* __restrict__ Pe, int count)
{
    __shared__ float sh[8][CH];
    int g = threadIdx.x >> 5;
    int t = threadIdx.x & 31;
    int i = blockIdx.x*8 + g;
    sh[g][t] = (i < count) ? hf[(size_t)i*CH + t] : 0.f;
    __syncthreads();
    float z = nb1[t];
    float pe = 0.f;
    #pragma unroll
    for (int k = 0; k < CH; k++){
        float hk = sh[g][k];
        z  = fmaf(hk, nW1[k*CH + t], z);
        pe = fmaf(hk, eW1[k*CH + t], pe);
    }
    if (i < count) Pe[(size_t)i*CH + t] = f2bf(pe);
    z = fmaxf(z, 0.f);
    float r0 = z * nW2[t*2 + 0];
    float r1 = z * nW2[t*2 + 1];
    #pragma unroll
    for (int o = 1; o < 32; o <<= 1){
        r0 += __shfl_xor(r0, o);
        r1 += __shfl_xor(r1, o);
    }
    if (t == 0 && i < count){
        float z0 = r0 + nb2[0], z1 = r1 + nb2[1];
        float mm = fmaxf(z0, z1);
        float lse = mm + __logf(__expf(z0 - mm) + __expf(z1 - mm));
        out[(size_t)i*2 + 0] = z0 - lse;
        out[(size_t)i*2 + 1] = z1 - lse;
    }
}

// ---------- edge head finisher: 4 lanes per edge (quad), bf16 P gathers ----------
__global__ __launch_bounds__(256) void k_edgefin(
        const unsigned short* __restrict__ P,
        const int* __restrict__ src, const int* __restrict__ dst,
        const float* __restrict__ b1, const float* __restrict__ W2,
        const float* __restrict__ b2, float* __restrict__ out, int E)
{
    int gt = blockIdx.x*256 + threadIdx.x;
    int e = gt >> 2, sub = gt & 3;
    if (e >= E) return;
    int s = src[e], d = dst[e];
    int c0 = sub*8;
    uint4 us = *reinterpret_cast<const uint4*>(P + (size_t)s*CH + c0);
    uint4 ud = *reinterpret_cast<const uint4*>(P + (size_t)d*CH + c0);
    float ps[8], pd[8];
    unpk8(us, ps); unpk8(ud, pd);
    const float* bp = b1 + c0;
    float4 bb0 = ld4(bp), bb1 = ld4(bp + 4);
    float b8[8] = {bb0.x, bb0.y, bb0.z, bb0.w, bb1.x, bb1.y, bb1.z, bb1.w};
    float r0 = 0.f, r1 = 0.f;
    #pragma unroll
    for (int c = 0; c < 8; c++){
        float z = fmaxf(ps[c] + pd[c] + b8[c], 0.f);
        r0 = fmaf(z, W2[(c0+c)*2 + 0], r0);
        r1 = fmaf(z, W2[(c0+c)*2 + 1], r1);
    }
    r0 = dpp_sum4(r0);
    r1 = dpp_sum4(r1);
    if (sub == 0){
        float z0 = r0 + b2[0], z1 = r1 + b2[1];
        float mm = fmaxf(z0, z1);
        float lse = mm + __logf(__expf(z0 - mm) + __expf(z1 - mm));
        float2 o2; o2.x = z0 - lse; o2.y = z1 - lse;
        *reinterpret_cast<float2*>(out + (size_t)e*2) = o2;
    }
}

extern "C" void kernel_launch(void* const* d_in, const int* in_sizes, int n_in,
                              void* d_out, int out_size, void* d_ws, size_t ws_size,
                              hipStream_t stream)
{
    const float* x     = (const float*)d_in[0];
    const int*   ei    = (const int*)d_in[1];
    const float* eattr = (const float*)d_in[2];
    int N = in_sizes[0] / 3;
    int E = in_sizes[2];
    const int* src0 = ei;
    const int* dst0 = ei + E;

    const float *Wl[3], *bl[3], *Wr[3], *br[3], *We[3], *att[3], *bias[3];
    for (int l = 0; l < 3; l++){
        int b = 3 + l*7;
        Wl[l]   = (const float*)d_in[b+0];
        bl[l]   = (const float*)d_in[b+1];
        Wr[l]   = (const float*)d_in[b+2];
        br[l]   = (const float*)d_in[b+3];
        We[l]   = (const float*)d_in[b+4];
        att[l]  = (const float*)d_in[b+5];
        bias[l] = (const float*)d_in[b+6];
    }
    const float* nhW1 = (const float*)d_in[24];
    const float* nhb1 = (const float*)d_in[25];
    const float* nhW2 = (const float*)d_in[26];
    const float* nhb2 = (const float*)d_in[27];
    const float* ehW1 = (const float*)d_in[28];
    const float* ehb1 = (const float*)d_in[29];
    const float* ehW2 = (const float*)d_in[30];
    const float* ehb2 = (const float*)d_in[31];

    char* ws = (char*)d_ws;
    auto alloc = [&](size_t bytes) -> char* {
        char* p = ws;
        ws += (bytes + 255) & ~(size_t)255;
        return p;
    };
    unsigned short* Hb  = (unsigned short*)alloc((size_t)N*HCDIM*2);  // layers 0/1 output (bf16)
    float* H0f          = (float*)alloc((size_t)N*CH*4);              // layer 2 output
    unsigned short* XL  = (unsigned short*)alloc((size_t)N*HCDIM*2);
    unsigned short* XR  = (unsigned short*)alloc((size_t)N*HCDIM*2);
    unsigned long long* degsum = (unsigned long long*)alloc((size_t)N*8);
    int*   rank     = (int*)alloc((size_t)E*4);
    float* lattr    = (float*)alloc((size_t)N*4);
    int*   offs     = (int*)alloc((size_t)(N+1)*4);
    int*   partials = (int*)alloc((size_t)64*4);
    int2*  csr      = (int2*)alloc((size_t)E*8);
    unsigned short* Wt1 = (unsigned short*)alloc((size_t)512*HCDIM*2);
    unsigned short* Wt2 = (unsigned short*)alloc((size_t)512*HCDIM*2);
    unsigned short* Pe  = (unsigned short*)alloc((size_t)N*CH*2);

    int nb = (N + 1023) / 1024;   // scan blocks (25 for N=25000)
    int nbCount = (E + 255) / 256;
    int nbGemm  = (N + 15) / 16;
    int nbCvt   = 1024;

    // preprocessing: own zero kernel, then ONE fused launch
    k_zero<<<(N + 255)/256, 256, 0, stream>>>(degsum, N);
    k_fused_pre<<<nbCount + nbGemm + nbCvt, 256, 0, stream>>>(
        dst0, eattr, degsum, rank, E,
        x, Wl[0], bl[0], Wr[0], br[0], XL, XR, N,
        Wl[1], Wr[1], Wl[2], Wr[2], Wt1, Wt2,
        nbCount, nbGemm);
    k_scan1<<<nb, 1024, 0, stream>>>(degsum, offs, lattr, partials, N);
    k_scan3<<<nb, 1024, 0, stream>>>(offs, partials, N);
    k_scatter<<<(E+255)/256, 256, 0, stream>>>(src0, dst0, eattr, offs, rank, csr, E);

    int gemm_grid = ((N + BM - 1) / BM) * 4;   // 1D, XCD-swizzled in-kernel
    int gat_grid  = (N < 4096) ? N : 4096;     // persistent one-wave blocks

    // layer 0 gat
    k_gat<<<gat_grid, 64, 0, stream>>>(XL, XR, csr, offs, lattr,
                                       We[0], att[0], bias[0], Hb, nullptr, N, 1);
    // layer 1 (din=256, bf16 MFMA)
    k_mfma_gemm<<<gemm_grid, 256, 0, stream>>>(Hb, Wt1, bl[1], br[1], XL, XR, N);
    k_gat<<<gat_grid, 64, 0, stream>>>(XL, XR, csr, offs, lattr,
                                       We[1], att[1], bias[1], Hb, nullptr, N, 1);
    // layer 2 (din=256, bf16 MFMA, concat=false -> f32 N x 32)
    k_mfma_gemm<<<gemm_grid, 256, 0, stream>>>(Hb, Wt2, bl[2], br[2], XL, XR, N);
    k_gat<<<gat_grid, 64, 0, stream>>>(XL, XR, csr, offs, lattr,
                                       We[2], att[2], bias[2], nullptr, H0f, N, 0);

    // fused node head + edge-P precompute, then per-edge finisher (4 lanes/edge)
    float* out_node = (float*)d_out;
    float* out_edge = out_node + (size_t)N*2;
    k_heads<<<(N+7)/8, 256, 0, stream>>>(H0f, nhW1, nhb1, nhW2, nhb2, ehW1,
                                         out_node, Pe, N);
    k_edgefin<<<((size_t)E*4 + 255)/256, 256, 0, stream>>>(Pe, src0, dst0,
                                                           ehb1, ehW2, ehb2, out_edge, E);
}

// Round 21
// 245.586 us; speedup vs baseline: 1.1635x; 1.1635x over previous
//
#include <hip/hip_runtime.h>
#include <math.h>

#define HCDIM 256   // H*C
#define HEADS 8
#define CH 32
#define NEG 0.2f
#define LOG2E 1.4426950408889634f

typedef __attribute__((ext_vector_type(8))) short bf16x8;
typedef __attribute__((ext_vector_type(4))) float f32x4;

__device__ __forceinline__ float4 ld4(const float* p){ return *reinterpret_cast<const float4*>(p); }
__device__ __forceinline__ void st4(float* p, float a, float b, float c, float d){
    float4 v; v.x=a; v.y=b; v.z=c; v.w=d; *reinterpret_cast<float4*>(p)=v;
}
__device__ __forceinline__ unsigned short f2bf(float f){
    union { float f; unsigned u; } x; x.f = f;
    unsigned r = x.u + 0x7fff + ((x.u >> 16) & 1);   // RNE
    return (unsigned short)(r >> 16);
}
__device__ __forceinline__ float bf2f(unsigned short u){
    union { unsigned u; float f; } x; x.u = (unsigned)u << 16; return x.f;
}
// unpack 8 bf16 (uint4) -> 8 f32
__device__ __forceinline__ void unpk8(uint4 u, float* x){
    x[0] = __uint_as_float(u.x << 16); x[1] = __uint_as_float(u.x & 0xffff0000u);
    x[2] = __uint_as_float(u.y << 16); x[3] = __uint_as_float(u.y & 0xffff0000u);
    x[4] = __uint_as_float(u.z << 16); x[5] = __uint_as_float(u.z & 0xffff0000u);
    x[6] = __uint_as_float(u.w << 16); x[7] = __uint_as_float(u.w & 0xffff0000u);
}
// exact 4-lane (quad) sum via DPP
__device__ __forceinline__ float dpp_sum4(float p){
    p += __int_as_float(__builtin_amdgcn_mov_dpp(__float_as_int(p), 0xB1, 0xf, 0xf, true));
    p += __int_as_float(__builtin_amdgcn_mov_dpp(__float_as_int(p), 0x4E, 0xf, 0xf, true));
    return p;
}

// ---------- zero degsum ----------
__global__ void k_zero(unsigned long long* __restrict__ p, int n){
    int i = blockIdx.x*blockDim.x + threadIdx.x;
    if (i < n) p[i] = 0ULL;
}

// ---------- FUSED preprocessing launch: count | layer-0 dual GEMM (din=3) | cvtw2 ----------
__global__ __launch_bounds__(256) void k_fused_pre(
        const int* __restrict__ dst, const float* __restrict__ eattr,
        unsigned long long* __restrict__ degsum, int* __restrict__ rank, int E,
        const float* __restrict__ x,
        const float* __restrict__ Wl0, const float* __restrict__ bl0,
        const float* __restrict__ Wr0, const float* __restrict__ br0,
        unsigned short* __restrict__ XL, unsigned short* __restrict__ XR, int N,
        const float* __restrict__ Wl1, const float* __restrict__ Wr1,
        const float* __restrict__ Wl2, const float* __restrict__ Wr2,
        unsigned short* __restrict__ Wt1, unsigned short* __restrict__ Wt2,
        int nbCount, int nbGemm)
{
    __shared__ float hs[48];
    int b = blockIdx.x;
    int tid = threadIdx.x;
    if (b < nbCount){
        // ONE packed 64-bit atomic per edge: hi bits deg, low 40 = lsum (2^-20 fp).
        int e = b*256 + tid;
        if (e < E){
            int d = dst[e];
            unsigned long long pk = (1ULL << 40) |
                (unsigned long long)__float2uint_rn(eattr[e] * 1048576.0f);
            unsigned long long old = atomicAdd(&degsum[d], pk);
            rank[e] = (int)(old >> 40);
        }
    } else if (b < nbCount + nbGemm){
        int gb = b - nbCount;
        int row0 = gb * 16;
        if (tid < 48){
            int r = tid / 3, c = tid - r*3;
            int row = row0 + r;
            hs[tid] = (row < N) ? x[(size_t)row*3 + c] : 0.f;
        }
        __syncthreads();
        int j = tid;
        float wl0 = Wl0[j], wl1 = Wl0[256 + j], wl2 = Wl0[512 + j];
        float wr0 = Wr0[j], wr1 = Wr0[256 + j], wr2 = Wr0[512 + j];
        float blj = bl0[j], brj = br0[j];
        #pragma unroll
        for (int r = 0; r < 16; r++){
            int row = row0 + r;
            if (row < N){
                float h0 = hs[r*3], h1 = hs[r*3+1], h2 = hs[r*3+2];
                float al = blj + h0*wl0 + h1*wl1 + h2*wl2;
                float ar = brj + h0*wr0 + h1*wr1 + h2*wr2;
                XL[(size_t)row*HCDIM + j] = f2bf(al);
                XR[(size_t)row*HCDIM + j] = f2bf(ar);
            }
        }
    } else {
        int idx = (b - nbCount - nbGemm)*256 + tid;   // [0, 2*512*256)
        int half = idx >> 17;
        int j = idx & 131071;
        int nout = j >> 8, k = j & 255;
        const float* Wl = half ? Wl2 : Wl1;
        const float* Wr = half ? Wr2 : Wr1;
        float v = (nout < 256) ? Wl[k*HCDIM + nout] : Wr[k*HCDIM + (nout - 256)];
        (half ? Wt2 : Wt1)[j] = f2bf(v);
    }
}

// ---- scan pass 1: per-block inclusive scan + block totals + lattr ----
__global__ __launch_bounds__(1024) void k_scan1(
        const unsigned long long* __restrict__ degsum,
        int* __restrict__ offs, float* __restrict__ lattr,
        int* __restrict__ partials, int n){
    __shared__ int wsum[16];
    int tid = threadIdx.x;
    int i = blockIdx.x*1024 + tid;
    int lane = tid & 63, wid = tid >> 6;
    int x = 0;
    if (i < n){
        unsigned long long ds = degsum[i];
        x = (int)(ds >> 40);
        float ls = (float)(ds & ((1ULL << 40) - 1)) * (1.0f/1048576.0f);
        lattr[i] = ls / fmaxf((float)x, 1.0f);
    }
    int v = x;
    #pragma unroll
    for (int o = 1; o < 64; o <<= 1){
        int y = __shfl_up(v, o);
        if (lane >= o) v += y;
    }
    if (lane == 63) wsum[wid] = v;
    __syncthreads();
    if (wid == 0 && lane < 16){
        int w = wsum[lane];
        #pragma unroll
        for (int o = 1; o < 16; o <<= 1){
            int y = __shfl_up(w, o);
            if (lane >= o) w += y;
        }
        wsum[lane] = w;
    }
    __syncthreads();
    int incl = v + (wid > 0 ? wsum[wid-1] : 0);
    if (i < n) offs[i+1] = incl;
    if (tid == 1023) partials[blockIdx.x] = incl;
}

// ---- scan pass 2: add block base (computed in-kernel; nb <= 64) ----
__global__ __launch_bounds__(1024) void k_scan3(int* __restrict__ offs,
                                                const int* __restrict__ partials, int n){
    __shared__ int sbase;
    if (threadIdx.x < 64){
        int lane = threadIdx.x;
        int vv = (lane < (int)blockIdx.x) ? partials[lane] : 0;
        #pragma unroll
        for (int o = 1; o < 64; o <<= 1) vv += __shfl_xor(vv, o);
        if (lane == 0) sbase = vv;
    }
    __syncthreads();
    int i = blockIdx.x*1024 + threadIdx.x;
    if (i < n) offs[i+1] += sbase;
    if (i == 0) offs[0] = 0;
}

// csr.x holds PRE-SHIFTED byte offset (src * HCDIM * 2); NO atomics.
__global__ void k_scatter(const int* __restrict__ src, const int* __restrict__ dst,
                          const float* __restrict__ eattr, const int* __restrict__ offs,
                          const int* __restrict__ rank, int2* csr, int E){
    int e = blockIdx.x*blockDim.x + threadIdx.x;
    if (e < E){
        int d = dst[e];
        int pos = offs[d] + rank[e];
        int2 pk; pk.x = src[e] << 9; pk.y = __float_as_int(eattr[e]);
        csr[pos] = pk;
    }
}

// ---------- bf16 MFMA GEMM: [xl | xr] = h @ [Wl | Wr] + [bl | br] ----------
// 1D grid with XCD-aware bijective swizzle: the 4 col-chunks sharing the same
// A-rows land on the SAME XCD -> A fetched once per XCD L2, not 4x.
#define BM 128
#define BN 128
#define BK 32
#define LDK 40   // padded LDS stride (bf16 elems)

__global__ __launch_bounds__(256) void k_mfma_gemm(
        const unsigned short* __restrict__ h,
        const unsigned short* __restrict__ Wt,
        const float* __restrict__ bl, const float* __restrict__ br,
        unsigned short* __restrict__ xl, unsigned short* __restrict__ xr, int n)
{
    __shared__ unsigned short As[BM*LDK];
    __shared__ unsigned short Bs[BN*LDK];
    int tid = threadIdx.x;
    int total = gridDim.x;
    int q = total >> 3, rr = total & 7;
    int xcd = blockIdx.x & 7, slot = blockIdx.x >> 3;
    int logical = (xcd < rr ? xcd*(q+1) : rr*(q+1) + (xcd-rr)*q) + slot;
    int row0 = (logical >> 2) * BM;
    int col0 = (logical & 3) * BN;      // 0,128,256,384 over [Wl|Wr]

    int l = tid & 63, w = tid >> 6;
    int wm = (w >> 1) * 64, wn = (w & 1) * 64;

    f32x4 acc[4][4] = {};

    int srow = tid >> 1;
    int skoff = (tid & 1) * 16;

    for (int kt = 0; kt < 8; ++kt){
        int kb = kt * BK;
        uint4 av0, av1;
        int grow = row0 + srow;
        if (grow < n){
            const uint4* ap = reinterpret_cast<const uint4*>(h + (size_t)grow*HCDIM + kb + skoff);
            av0 = ap[0]; av1 = ap[1];
        } else {
            av0.x=av0.y=av0.z=av0.w=0u; av1 = av0;
        }
        const uint4* bp = reinterpret_cast<const uint4*>(Wt + (size_t)(col0+srow)*HCDIM + kb + skoff);
        uint4 bv0 = bp[0], bv1 = bp[1];

        __syncthreads();   // previous iteration's LDS reads complete

        *reinterpret_cast<uint4*>(&As[srow*LDK + skoff])     = av0;
        *reinterpret_cast<uint4*>(&As[srow*LDK + skoff + 8]) = av1;
        *reinterpret_cast<uint4*>(&Bs[srow*LDK + skoff])     = bv0;
        *reinterpret_cast<uint4*>(&Bs[srow*LDK + skoff + 8]) = bv1;

        __syncthreads();

        bf16x8 af[4], bfr[4];
        #pragma unroll
        for (int m = 0; m < 4; m++)
            af[m] = *reinterpret_cast<const bf16x8*>(&As[(wm + m*16 + (l & 15))*LDK + ((l >> 4)*8)]);
        #pragma unroll
        for (int nn = 0; nn < 4; nn++)
            bfr[nn] = *reinterpret_cast<const bf16x8*>(&Bs[(wn + nn*16 + (l & 15))*LDK + ((l >> 4)*8)]);
        #pragma unroll
        for (int m = 0; m < 4; m++)
            #pragma unroll
            for (int nn = 0; nn < 4; nn++)
                acc[m][nn] = __builtin_amdgcn_mfma_f32_16x16x32_bf16(af[m], bfr[nn], acc[m][nn], 0, 0, 0);
    }

    unsigned short* dstp; const float* biasp; int cbase;
    if (col0 < 256){ dstp = xl; biasp = bl; cbase = col0; }
    else           { dstp = xr; biasp = br; cbase = col0 - 256; }

    #pragma unroll
    for (int nn = 0; nn < 4; nn++){
        int gc = cbase + wn + nn*16 + (l & 15);
        float bb = biasp[gc];
        #pragma unroll
        for (int m = 0; m < 4; m++){
            int r0 = row0 + wm + m*16 + ((l >> 4) * 4);
            #pragma unroll
            for (int v = 0; v < 4; v++){
                int rr2 = r0 + v;
                if (rr2 < n) dstp[(size_t)rr2*HCDIM + gc] = f2bf(acc[m][nn][v] + bb);
            }
        }
    }
}

// ---------- fused GATv2 edge kernel ----------
// ONE wave per BLOCK (64 threads), grid = N: blocks retire independently and the
// 25k-block pool continuously backfills CU slots (vs persistent grid: no backfill,
// R20 regression). TWO edges per wave-step (lanes 0-31 / 32-63), each lane owns
// 8 channels. 2-deep software pipeline; quad-DPP logit reduce; no-max softmax.
__global__ __launch_bounds__(64) void k_gat(
        const unsigned short* __restrict__ xl, const unsigned short* __restrict__ xr,
        const int2* __restrict__ csr,
        const int* __restrict__ offs, const float* __restrict__ lattr,
        const float* __restrict__ We, const float* __restrict__ att,
        const float* __restrict__ bias,
        unsigned short* __restrict__ hout_bf, float* __restrict__ hout_f,
        int n, int concat)
{
    int lane = threadIdx.x;
    int v = blockIdx.x;
    if (v >= n) return;
    int sub = lane >> 5;             // edge slot (0/1)
    int l5  = lane & 31;             // channel group: ch [l5*8, l5*8+8)
    const char* xlb = reinterpret_cast<const char*>(xl);
    const size_t cbb = (size_t)l5 * 16;   // byte offset within 512B row

    float We8[8], at8[8], xr8[8];
    {
        const float* wp = We + l5*8;
        const float* ap = att + l5*8;
        #pragma unroll
        for (int c = 0; c < 8; c++){ We8[c] = wp[c]; at8[c] = ap[c]*LOG2E; }
        uint4 u = *reinterpret_cast<const uint4*>(xr + (size_t)v*HCDIM + l5*8);
        unpk8(u, xr8);
    }
    int pbeg = offs[v], pend = offs[v+1];
    float la = lattr[v];

    float s = 0.f;
    float acc[8] = {0.f,0.f,0.f,0.f,0.f,0.f,0.f,0.f};

    auto estep = [&](uint4 xu, float ea){
        float x8[8];
        unpk8(xu, x8);
        float part = 0.f;
        #pragma unroll
        for (int c = 0; c < 8; c++){
            float t = x8[c] + fmaf(ea, We8[c], xr8[c]);
            t = fmaxf(t, NEG*t);              // leaky relu, slope<1
            part = fmaf(t, at8[c], part);
        }
        part = dpp_sum4(part);               // head logit (log2 units)
        float w = __builtin_amdgcn_exp2f(part);
        s += w;
        #pragma unroll
        for (int c = 0; c < 8; c++) acc[c] = fmaf(w, x8[c], acc[c]);
    };

    // prologue: slot A = self-loop, slot B = first real edge
    {
        uint4 xu; float ea; bool act;
        if (sub == 0){
            xu = *reinterpret_cast<const uint4*>(xlb + ((size_t)v << 9) + cbb);
            ea = la; act = true;
        } else {
            act = (pbeg < pend);
            if (act){
                int2 e = csr[pbeg];
                xu = *reinterpret_cast<const uint4*>(xlb + (size_t)(unsigned)e.x + cbb);
                ea = __int_as_float(e.y);
            }
        }
        if (act) estep(xu, ea);
    }

    // main loop: 2 edges per step, 2-deep software pipeline
    int p = pbeg + 1;                 // uniform across wave
    int2 e0, e1; uint4 x0, x1; bool a0 = false, a1 = false;
    {
        int i0 = p + sub;
        a0 = (i0 < pend);
        if (a0){
            e0 = csr[i0];
            x0 = *reinterpret_cast<const uint4*>(xlb + (size_t)(unsigned)e0.x + cbb);
        }
        int i1 = p + 2 + sub;
        a1 = (i1 < pend);
        if (a1){
            e1 = csr[i1];
            x1 = *reinterpret_cast<const uint4*>(xlb + (size_t)(unsigned)e1.x + cbb);
        }
    }
    for (; p < pend; p += 2){
        uint4 cx = x0; float cea = __int_as_float(e0.y); bool ca = a0;
        x0 = x1; e0 = e1; a0 = a1;
        int nx = p + 4 + sub;
        a1 = (nx < pend);
        if (a1){
            e1 = csr[nx];
            x1 = *reinterpret_cast<const uint4*>(xlb + (size_t)(unsigned)e1.x + cbb);
        }
        if (ca) estep(cx, cea);
    }

    // merge the two edge-slot halves (lane l <-> lane l^32)
    s += __shfl_xor(s, 32);
    #pragma unroll
    for (int c = 0; c < 8; c++) acc[c] += __shfl_xor(acc[c], 32);

    float inv = 1.f / s;
    if (concat){
        if (sub == 0){
            const float* bp = bias + l5*8;
            float4 b0 = ld4(bp), b1 = ld4(bp + 4);
            float r0 = fmaxf(fmaf(acc[0], inv, b0.x), 0.f);
            float r1 = fmaxf(fmaf(acc[1], inv, b0.y), 0.f);
            float r2 = fmaxf(fmaf(acc[2], inv, b0.z), 0.f);
            float r3 = fmaxf(fmaf(acc[3], inv, b0.w), 0.f);
            float r4 = fmaxf(fmaf(acc[4], inv, b1.x), 0.f);
            float r5 = fmaxf(fmaf(acc[5], inv, b1.y), 0.f);
            float r6 = fmaxf(fmaf(acc[6], inv, b1.z), 0.f);
            float r7 = fmaxf(fmaf(acc[7], inv, b1.w), 0.f);
            uint4 o;
            o.x = (unsigned)f2bf(r0) | ((unsigned)f2bf(r1) << 16);
            o.y = (unsigned)f2bf(r2) | ((unsigned)f2bf(r3) << 16);
            o.z = (unsigned)f2bf(r4) | ((unsigned)f2bf(r5) << 16);
            o.w = (unsigned)f2bf(r6) | ((unsigned)f2bf(r7) << 16);
            *reinterpret_cast<uint4*>(hout_bf + (size_t)v*HCDIM + l5*8) = o;
        }
    } else {
        float o8[8];
        #pragma unroll
        for (int c = 0; c < 8; c++) o8[c] = acc[c]*inv;   // normalize per head first
        #pragma unroll
        for (int m = 4; m <= 16; m <<= 1)
            #pragma unroll
            for (int c = 0; c < 8; c++) o8[c] += __shfl_xor(o8[c], m);  // sum heads
        if (lane < 4){
            const float* bp = bias + lane*8;
            float4 b0 = ld4(bp), b1 = ld4(bp + 4);
            float* op = hout_f + (size_t)v*CH + lane*8;
            st4(op,   fmaxf(fmaf(o8[0], 0.125f, b0.x), 0.f),
                      fmaxf(fmaf(o8[1], 0.125f, b0.y), 0.f),
                      fmaxf(fmaf(o8[2], 0.125f, b0.z), 0.f),
                      fmaxf(fmaf(o8[3], 0.125f, b0.w), 0.f));
            st4(op+4, fmaxf(fmaf(o8[4], 0.125f, b1.x), 0.f),
                      fmaxf(fmaf(o8[5], 0.125f, b1.y), 0.f),
                      fmaxf(fmaf(o8[6], 0.125f, b1.z), 0.f),
                      fmaxf(fmaf(o8[7], 0.125f, b1.w), 0.f));
        }
    }
}

// ---------- fused heads stage 1: node log-softmax out + Pe = h @ ehW1 (bf16) ----------
__global__ __launch_bounds__(256) void k_heads(
        const float* __restrict__ hf,
        const float* __restrict__ nW1, const float* __restrict__ nb1,
        const float* __restrict__ nW2, const float* __restrict__ nb2,
        const float* __restrict__ eW1,
        float* __restrict__ out, unsigned short* __restrict__ Pe, int count)
{
    __shared__ float sh[8][CH];
    int g = threadIdx.x >> 5;
    int t = threadIdx.x & 31;
    int i = blockIdx.x*8 + g;
    sh[g][t] = (i < count) ? hf[(size_t)i*CH + t] : 0.f;
    __syncthreads();
    float z = nb1[t];
    float pe = 0.f;
    #pragma unroll
    for (int k = 0; k < CH; k++){
        float hk = sh[g][k];
        z  = fmaf(hk, nW1[k*CH + t], z);
        pe = fmaf(hk, eW1[k*CH + t], pe);
    }
    if (i < count) Pe[(size_t)i*CH + t] = f2bf(pe);
    z = fmaxf(z, 0.f);
    float r0 = z * nW2[t*2 + 0];
    float r1 = z * nW2[t*2 + 1];
    #pragma unroll
    for (int o = 1; o < 32; o <<= 1){
        r0 += __shfl_xor(r0, o);
        r1 += __shfl_xor(r1, o);
    }
    if (t == 0 && i < count){
        float z0 = r0 + nb2[0], z1 = r1 + nb2[1];
        float mm = fmaxf(z0, z1);
        float lse = mm + __logf(__expf(z0 - mm) + __expf(z1 - mm));
        out[(size_t)i*2 + 0] = z0 - lse;
        out[(size_t)i*2 + 1] = z1 - lse;
    }
}

// ---------- edge head finisher: 4 lanes per edge (quad), bf16 P gathers ----------
__global__ __launch_bounds__(256) void k_edgefin(
        const unsigned short* __restrict__ P,
        const int* __restrict__ src, const int* __restrict__ dst,
        const float* __restrict__ b1, const float* __restrict__ W2,
        const float* __restrict__ b2, float* __restrict__ out, int E)
{
    int gt = blockIdx.x*256 + threadIdx.x;
    int e = gt >> 2, sub = gt & 3;
    if (e >= E) return;
    int s = src[e], d = dst[e];
    int c0 = sub*8;
    uint4 us = *reinterpret_cast<const uint4*>(P + (size_t)s*CH + c0);
    uint4 ud = *reinterpret_cast<const uint4*>(P + (size_t)d*CH + c0);
    float ps[8], pd[8];
    unpk8(us, ps); unpk8(ud, pd);
    const float* bp = b1 + c0;
    float4 bb0 = ld4(bp), bb1 = ld4(bp + 4);
    float b8[8] = {bb0.x, bb0.y, bb0.z, bb0.w, bb1.x, bb1.y, bb1.z, bb1.w};
    float r0 = 0.f, r1 = 0.f;
    #pragma unroll
    for (int c = 0; c < 8; c++){
        float z = fmaxf(ps[c] + pd[c] + b8[c], 0.f);
        r0 = fmaf(z, W2[(c0+c)*2 + 0], r0);
        r1 = fmaf(z, W2[(c0+c)*2 + 1], r1);
    }
    r0 = dpp_sum4(r0);
    r1 = dpp_sum4(r1);
    if (sub == 0){
        float z0 = r0 + b2[0], z1 = r1 + b2[1];
        float mm = fmaxf(z0, z1);
        float lse = mm + __logf(__expf(z0 - mm) + __expf(z1 - mm));
        float2 o2; o2.x = z0 - lse; o2.y = z1 - lse;
        *reinterpret_cast<float2*>(out + (size_t)e*2) = o2;
    }
}

extern "C" void kernel_launch(void* const* d_in, const int* in_sizes, int n_in,
                              void* d_out, int out_size, void* d_ws, size_t ws_size,
                              hipStream_t stream)
{
    const float* x     = (const float*)d_in[0];
    const int*   ei    = (const int*)d_in[1];
    const float* eattr = (const float*)d_in[2];
    int N = in_sizes[0] / 3;
    int E = in_sizes[2];
    const int* src0 = ei;
    const int* dst0 = ei + E;

    const float *Wl[3], *bl[3], *Wr[3], *br[3], *We[3], *att[3], *bias[3];
    for (int l = 0; l < 3; l++){
        int b = 3 + l*7;
        Wl[l]   = (const float*)d_in[b+0];
        bl[l]   = (const float*)d_in[b+1];
        Wr[l]   = (const float*)d_in[b+2];
        br[l]   = (const float*)d_in[b+3];
        We[l]   = (const float*)d_in[b+4];
        att[l]  = (const float*)d_in[b+5];
        bias[l] = (const float*)d_in[b+6];
    }
    const float* nhW1 = (const float*)d_in[24];
    const float* nhb1 = (const float*)d_in[25];
    const float* nhW2 = (const float*)d_in[26];
    const float* nhb2 = (const float*)d_in[27];
    const float* ehW1 = (const float*)d_in[28];
    const float* ehb1 = (const float*)d_in[29];
    const float* ehW2 = (const float*)d_in[30];
    const float* ehb2 = (const float*)d_in[31];

    char* ws = (char*)d_ws;
    auto alloc = [&](size_t bytes) -> char* {
        char* p = ws;
        ws += (bytes + 255) & ~(size_t)255;
        return p;
    };
    unsigned short* Hb  = (unsigned short*)alloc((size_t)N*HCDIM*2);  // layers 0/1 output (bf16)
    float* H0f          = (float*)alloc((size_t)N*CH*4);              // layer 2 output
    unsigned short* XL  = (unsigned short*)alloc((size_t)N*HCDIM*2);
    unsigned short* XR  = (unsigned short*)alloc((size_t)N*HCDIM*2);
    unsigned long long* degsum = (unsigned long long*)alloc((size_t)N*8);
    int*   rank     = (int*)alloc((size_t)E*4);
    float* lattr    = (float*)alloc((size_t)N*4);
    int*   offs     = (int*)alloc((size_t)(N+1)*4);
    int*   partials = (int*)alloc((size_t)64*4);
    int2*  csr      = (int2*)alloc((size_t)E*8);
    unsigned short* Wt1 = (unsigned short*)alloc((size_t)512*HCDIM*2);
    unsigned short* Wt2 = (unsigned short*)alloc((size_t)512*HCDIM*2);
    unsigned short* Pe  = (unsigned short*)alloc((size_t)N*CH*2);

    int nb = (N + 1023) / 1024;   // scan blocks (25 for N=25000)
    int nbCount = (E + 255) / 256;
    int nbGemm  = (N + 15) / 16;
    int nbCvt   = 1024;

    // preprocessing: own zero kernel, then ONE fused launch
    k_zero<<<(N + 255)/256, 256, 0, stream>>>(degsum, N);
    k_fused_pre<<<nbCount + nbGemm + nbCvt, 256, 0, stream>>>(
        dst0, eattr, degsum, rank, E,
        x, Wl[0], bl[0], Wr[0], br[0], XL, XR, N,
        Wl[1], Wr[1], Wl[2], Wr[2], Wt1, Wt2,
        nbCount, nbGemm);
    k_scan1<<<nb, 1024, 0, stream>>>(degsum, offs, lattr, partials, N);
    k_scan3<<<nb, 1024, 0, stream>>>(offs, partials, N);
    k_scatter<<<(E+255)/256, 256, 0, stream>>>(src0, dst0, eattr, offs, rank, csr, E);

    int gemm_grid = ((N + BM - 1) / BM) * 4;   // 1D, XCD-swizzled in-kernel

    // layer 0 gat (1 wave per block, grid = N)
    k_gat<<<N, 64, 0, stream>>>(XL, XR, csr, offs, lattr,
                                We[0], att[0], bias[0], Hb, nullptr, N, 1);
    // layer 1 (din=256, bf16 MFMA)
    k_mfma_gemm<<<gemm_grid, 256, 0, stream>>>(Hb, Wt1, bl[1], br[1], XL, XR, N);
    k_gat<<<N, 64, 0, stream>>>(XL, XR, csr, offs, lattr,
                                We[1], att[1], bias[1], Hb, nullptr, N, 1);
    // layer 2 (din=256, bf16 MFMA, concat=false -> f32 N x 32)
    k_mfma_gemm<<<gemm_grid, 256, 0, stream>>>(Hb, Wt2, bl[2], br[2], XL, XR, N);
    k_gat<<<N, 64, 0, stream>>>(XL, XR, csr, offs, lattr,
                                We[2], att[2], bias[2], nullptr, H0f, N, 0);

    // fused node head + edge-P precompute, then per-edge finisher (4 lanes/edge)
    float* out_node = (float*)d_out;
    float* out_edge = out_node + (size_t)N*2;
    k_heads<<<(N+7)/8, 256, 0, stream>>>(H0f, nhW1, nhb1, nhW2, nhb2, ehW1,
                                         out_node, Pe, N);
    k_edgefin<<<((size_t)E*4 + 255)/256, 256, 0, stream>>>(Pe, src0, dst0,
                                                           ehb1, ehW2, ehb2, out_edge, E);
}